// Round 6
// baseline (208.852 us; speedup 1.0000x reference)
//
#include <hip/hip_runtime.h>

// QuantizeEMAReset forward (eval): VQ quantize + commit loss + perplexity/usage.
// z: [16,4096,64] fp32 -> N=65536 tokens, C=64. codebook: [1024,64] fp32.
// out: [z_q_bar (4194304 f32), commit_loss, ppl, usage] flat.
//
// R6: barrier-free MFMA main loop. Codebook hi/lo (256 KB) is L2-resident ->
// lanes load A-frags straight from global (no LDS staging, no per-tile
// __syncthreads; R5 was barrier-bound: MfmaUtil 12%, VALUBusy 21%).
// Register double-buffer (unroll-2, distance-1 prefetch); a2 split into two
// independent accs (dep chain 4->2). Near-ties exactly rescored in fp32.
//
// ws float-index map:
//   [0,1024)      cnorm
//   [1024,2048)   counts
//   [2048,3072)   loss partials (per block)
//   3072          nflag (int)
//   [3073,7169)   flag list (int: tok | idx<<16)
//   [8192,40960)  cbh halves (65536)
//   [40960,73728) cbl halves (65536)   total 288 KB

typedef _Float16 half8 __attribute__((ext_vector_type(8)));
typedef float f32x4 __attribute__((ext_vector_type(4)));

#define NTOK 65536
#define KCODE 1024
#define OUT_SCALARS 4194304
#define MARGIN 1e-3f
#define FLAG_CAP 4096

#define WS_CNORM 0
#define WS_CNT   1024
#define WS_LOSS  2048
#define WS_NFLAG 3072
#define WS_FLAGS 3073
#define WS_CBH   8192
#define WS_CBL   40960

static __device__ __forceinline__ unsigned int order_key(float f) {
    unsigned int u = __float_as_uint(f);
    unsigned int mask = (u >> 31) ? 0xFFFFFFFFu : 0x80000000u;
    return u ^ mask;   // monotone: a<b (float) <=> key(a)<key(b) (uint)
}

__global__ void prep_kernel(const float* __restrict__ cb, float* __restrict__ ws) {
    const int k = blockIdx.x * 256 + threadIdx.x;   // 0..1023
    const float4* cb4 = (const float4*)cb;
    float s = 0.f;
#pragma unroll
    for (int j = 0; j < 16; ++j) {
        float4 v = cb4[k * 16 + j];
        s = fmaf(v.x, v.x, s);
        s = fmaf(v.y, v.y, s);
        s = fmaf(v.z, v.z, s);
        s = fmaf(v.w, v.w, s);
    }
    ws[k] = s;             // cnorm: exact R1 chain
    ws[WS_CNT + k] = 0.f;  // zero histogram
    if (k == 0) *(int*)(ws + WS_NFLAG) = 0;

    _Float16* cbh = (_Float16*)(ws + WS_CBH);
    _Float16* cbl = (_Float16*)(ws + WS_CBL);
#pragma unroll
    for (int j8 = 0; j8 < 8; ++j8) {
        float4 a = cb4[k * 16 + 2 * j8], b = cb4[k * 16 + 2 * j8 + 1];
        float xf[8] = {a.x, a.y, a.z, a.w, b.x, b.y, b.z, b.w};
        half8 h, lo;
#pragma unroll
        for (int i = 0; i < 8; ++i) {
            _Float16 hi = (_Float16)xf[i];
            h[i] = hi;
            lo[i] = (_Float16)((xf[i] - (float)hi) * 4096.f);  // scaled: no f16 denorm flush
        }
        *(half8*)(cbh + k * 64 + j8 * 8) = h;
        *(half8*)(cbl + k * 64 + j8 * 8) = lo;
    }
}

__launch_bounds__(256, 4)
__global__ void quant_kernel(const float* __restrict__ z,
                             const float* __restrict__ cb,
                             float* __restrict__ out,
                             float* __restrict__ ws) {
    const int t = threadIdx.x, blk = blockIdx.x;
    const int w = t >> 6, l = t & 63;
    const int cl = l & 15, g = l >> 4;        // MFMA col-lane, k-group
    const int tokL = w * 16 + cl;             // local token (this lane's B column)
    const int tokG = blk * 64 + tokL;

    __shared__ __align__(16) float x_lds[64 * 68];   // fp32 x, stride 68 (epilogue only)
    __shared__ int win[64];
    __shared__ float lsum[64];

    // ---- B fragments (persistent) + x_lds staging; covers each (tok,dim) once ----
    half8 zh[2], zl[2];
    {
        const float4* z4 = (const float4*)(z + (size_t)tokG * 64);
#pragma unroll
        for (int q = 0; q < 2; ++q) {
            float4 a = z4[2 * g + 8 * q], b = z4[2 * g + 8 * q + 1];
            *(float4*)&x_lds[tokL * 68 + g * 8 + 32 * q] = a;
            *(float4*)&x_lds[tokL * 68 + g * 8 + 32 * q + 4] = b;
            float xf[8] = {a.x, a.y, a.z, a.w, b.x, b.y, b.z, b.w};
#pragma unroll
            for (int i = 0; i < 8; ++i) {
                _Float16 h = (_Float16)xf[i];
                zh[q][i] = h;
                zl[q][i] = (_Float16)((xf[i] - (float)h) * 4096.f);
            }
        }
    }

    const _Float16* cbh = (const _Float16*)(ws + WS_CBH);
    const _Float16* cbl = (const _Float16*)(ws + WS_CBL);
    const int fo = cl * 64 + g * 8;   // per-lane fragment offset within a 16-code tile

    float d1 = 3.4e38f, d2 = 3.4e38f;
    int idx1 = 0;

#define LOADT(H0, H1, L0, L1, c0)                                   \
    H0 = *(const half8*)(cbh + (size_t)(c0) * 64 + fo);             \
    H1 = *(const half8*)(cbh + (size_t)(c0) * 64 + fo + 32);        \
    L0 = *(const half8*)(cbl + (size_t)(c0) * 64 + fo);             \
    L1 = *(const half8*)(cbl + (size_t)(c0) * 64 + fo + 32);

#define COMPUTE(H0, H1, L0, L1, c0) {                                          \
    f32x4 a1 = {0.f,0.f,0.f,0.f}, a2a = {0.f,0.f,0.f,0.f}, a2b = {0.f,0.f,0.f,0.f}; \
    a1  = __builtin_amdgcn_mfma_f32_16x16x32_f16(H0, zh[0], a1, 0, 0, 0);      \
    a1  = __builtin_amdgcn_mfma_f32_16x16x32_f16(H1, zh[1], a1, 0, 0, 0);      \
    a2a = __builtin_amdgcn_mfma_f32_16x16x32_f16(H0, zl[0], a2a, 0, 0, 0);     \
    a2a = __builtin_amdgcn_mfma_f32_16x16x32_f16(H1, zl[1], a2a, 0, 0, 0);     \
    a2b = __builtin_amdgcn_mfma_f32_16x16x32_f16(L0, zh[0], a2b, 0, 0, 0);     \
    a2b = __builtin_amdgcn_mfma_f32_16x16x32_f16(L1, zh[1], a2b, 0, 0, 0);     \
    const float4 cnv = *(const float4*)(ws + (c0) + 4 * g);                    \
    const float cna[4] = {cnv.x, cnv.y, cnv.z, cnv.w};                         \
    _Pragma("unroll")                                                          \
    for (int r = 0; r < 4; ++r) {                                              \
        float dot = fmaf(a2a[r] + a2b[r], 2.44140625e-4f, a1[r]);              \
        float d = fmaf(-2.f, dot, cna[r]);                                     \
        const int kidx = (c0) + 4 * g + r;                                     \
        bool lt = d < d1;                                                      \
        d2 = fminf(d2, fmaxf(d, d1));                                          \
        idx1 = lt ? kidx : idx1;                                               \
        d1 = fminf(d1, d);                                                     \
    } }

    half8 Ah0, Ah1, Al0, Al1, Bh0, Bh1, Bl0, Bl1;
    LOADT(Ah0, Ah1, Al0, Al1, 0)
    for (int t2 = 0; t2 < 64; t2 += 2) {
        LOADT(Bh0, Bh1, Bl0, Bl1, (t2 + 1) * 16)
        COMPUTE(Ah0, Ah1, Al0, Al1, t2 * 16)
        if (t2 + 2 < 64) { LOADT(Ah0, Ah1, Al0, Al1, (t2 + 2) * 16) }
        COMPUTE(Bh0, Bh1, Bl0, Bl1, (t2 + 1) * 16)
    }
#undef LOADT
#undef COMPUTE

    // ---- merge 4 lanes per token (lanes cl, cl+16, cl+32, cl+48) ----
    unsigned long long key = ((unsigned long long)order_key(d1) << 32) | (unsigned)idx1;
#pragma unroll
    for (int off = 16; off <= 32; off <<= 1) {
        unsigned long long ok = __shfl_xor(key, off, 64);
        float od1 = __shfl_xor(d1, off, 64);
        float od2 = __shfl_xor(d2, off, 64);
        d2 = fminf(fminf(d2, od2), fmaxf(d1, od1));  // 2nd-min of union
        d1 = fminf(d1, od1);
        key = ok < key ? ok : key;
    }
    if (l < 16) {
        const int idx = (int)(unsigned)(key & 0xFFFFFFFFull);
        win[tokL] = idx;
        atomicAdd(&ws[WS_CNT + idx], 1.f);   // integer-valued: exact, order-indep
        if (d2 - d1 < MARGIN) {              // near-tie: flag for exact rescore
            int slot = atomicAdd((int*)(ws + WS_NFLAG), 1);
            if (slot < FLAG_CAP)
                ((int*)(ws + WS_FLAGS))[slot] = tokG | (idx << 16);
        }
    }
    __syncthreads();

    // ---- fused epilogue: z_q_bar + commit-loss partial ----
    {
        const int tokr = t >> 2, fb = (t & 3) * 4;
        const int idx = win[tokr];
        const float4* cq = (const float4*)cb + (size_t)idx * 16;
        float4* o4 = (float4*)out + (size_t)(blk * 64 + tokr) * 16;
        float ss = 0.f;
#pragma unroll
        for (int j = 0; j < 4; ++j) {
            float4 xv = *(const float4*)&x_lds[tokr * 68 + (fb + j) * 4];
            float4 qv = cq[fb + j];
            float4 ov; float dx;
            dx = qv.x - xv.x; ov.x = xv.x + dx; ss = fmaf(dx, dx, ss);
            dx = qv.y - xv.y; ov.y = xv.y + dx; ss = fmaf(dx, dx, ss);
            dx = qv.z - xv.z; ov.z = xv.z + dx; ss = fmaf(dx, dx, ss);
            dx = qv.w - xv.w; ov.w = xv.w + dx; ss = fmaf(dx, dx, ss);
            o4[fb + j] = ov;
        }
        ss += __shfl_down(ss, 2, 64);
        ss += __shfl_down(ss, 1, 64);
        if ((t & 3) == 0) lsum[tokr] = ss * (1.f / 64.f);
    }
    __syncthreads();
    if (t < 64) {
        float v = lsum[t];
#pragma unroll
        for (int off = 32; off > 0; off >>= 1) v += __shfl_down(v, off, 64);
        if (t == 0) ws[WS_LOSS + blk] = v;
    }
}

// Exact fp32 rescore (R1 chain) for flagged near-tie tokens.
__global__ void rescue_kernel(const float* __restrict__ z,
                              const float* __restrict__ cb,
                              float* __restrict__ out,
                              float* __restrict__ ws) {
    const int t = threadIdx.x;
    int nf = *(const int*)(ws + WS_NFLAG);
    if (nf > FLAG_CAP) nf = FLAG_CAP;
    __shared__ float xs[64];
    __shared__ unsigned long long rk[256];
    const float4* cb4 = (const float4*)cb;

    for (int i = blockIdx.x; i < nf; i += 256) {
        const int e = ((const int*)(ws + WS_FLAGS))[i];
        const int tok = e & 0xFFFF, oldidx = e >> 16;
        __syncthreads();
        if (t < 16) *(float4*)&xs[t * 4] = ((const float4*)(z + (size_t)tok * 64))[t];
        __syncthreads();

        unsigned long long best = ~0ull;
#pragma unroll
        for (int kk = 0; kk < 4; ++kk) {
            const int k = t * 4 + kk;
            float s = 0.f;
#pragma unroll
            for (int j = 0; j < 16; ++j) {
                float4 c = cb4[(size_t)k * 16 + j];
                float4 xv = *(const float4*)&xs[j * 4];
                s = fmaf(xv.x, c.x, s);
                s = fmaf(xv.y, c.y, s);
                s = fmaf(xv.z, c.z, s);
                s = fmaf(xv.w, c.w, s);
            }
            float d = fmaf(-2.f, s, ws[k]);   // exact R1 distance
            unsigned long long kkey = ((unsigned long long)order_key(d) << 32) | (unsigned)k;
            best = kkey < best ? kkey : best;
        }
        rk[t] = best; __syncthreads();
        for (int sft = 128; sft > 0; sft >>= 1) {
            if (t < sft) { unsigned long long o = rk[t + sft]; if (o < rk[t]) rk[t] = o; }
            __syncthreads();
        }
        if (t == 0) {
            const int ni = (int)(unsigned)(rk[0] & 0xFFFFFFFFull);
            if (ni != oldidx) {
                atomicAdd(&ws[WS_CNT + oldidx], -1.f);
                atomicAdd(&ws[WS_CNT + ni], 1.f);
                const float4* co = cb4 + (size_t)oldidx * 16;
                const float4* cn = cb4 + (size_t)ni * 16;
                float4* o4 = (float4*)out + (size_t)tok * 16;
                float sg_o[4], sg_n[4];
#pragma unroll
                for (int gq = 0; gq < 4; ++gq) {
                    float so = 0.f, sn = 0.f;
#pragma unroll
                    for (int j = 0; j < 4; ++j) {
                        float4 xv = *(const float4*)&xs[(gq * 4 + j) * 4];
                        float4 qo = co[gq * 4 + j], qn = cn[gq * 4 + j];
                        float dx;
                        dx = qo.x - xv.x; so = fmaf(dx, dx, so);
                        dx = qo.y - xv.y; so = fmaf(dx, dx, so);
                        dx = qo.z - xv.z; so = fmaf(dx, dx, so);
                        dx = qo.w - xv.w; so = fmaf(dx, dx, so);
                        float4 ov;
                        dx = qn.x - xv.x; ov.x = xv.x + dx; sn = fmaf(dx, dx, sn);
                        dx = qn.y - xv.y; ov.y = xv.y + dx; sn = fmaf(dx, dx, sn);
                        dx = qn.z - xv.z; ov.z = xv.z + dx; sn = fmaf(dx, dx, sn);
                        dx = qn.w - xv.w; ov.w = xv.w + dx; sn = fmaf(dx, dx, sn);
                        o4[gq * 4 + j] = ov;
                    }
                    sg_o[gq] = so; sg_n[gq] = sn;
                }
                float sso = (sg_o[0] + sg_o[2]) + (sg_o[1] + sg_o[3]);  // match quant shfl tree
                float ssn = (sg_n[0] + sg_n[2]) + (sg_n[1] + sg_n[3]);
                atomicAdd(&ws[WS_LOSS + (tok >> 6)], (ssn - sso) * (1.f / 64.f));
            }
        }
    }
}

__global__ void final_kernel(const float* __restrict__ ws, float* __restrict__ out) {
    __shared__ float red[1024];
    const int t = threadIdx.x;
    const float c = ws[WS_CNT + t];

    red[t] = c; __syncthreads();
    for (int s = 512; s > 0; s >>= 1) { if (t < s) red[t] += red[t + s]; __syncthreads(); }
    const float total = fmaxf(red[0], 1e-6f);
    __syncthreads();

    const float p = c / total;
    red[t] = p * logf(p + 1e-7f); __syncthreads();
    for (int s = 512; s > 0; s >>= 1) { if (t < s) red[t] += red[t + s]; __syncthreads(); }
    const float ent = red[0];
    __syncthreads();

    red[t] = (c >= 1.f) ? 1.f : 0.f; __syncthreads();
    for (int s = 512; s > 0; s >>= 1) { if (t < s) red[t] += red[t + s]; __syncthreads(); }
    const float used = red[0];
    __syncthreads();

    red[t] = ws[WS_LOSS + t];   // 1024 block partials
    __syncthreads();
    for (int s = 512; s > 0; s >>= 1) { if (t < s) red[t] += red[t + s]; __syncthreads(); }

    if (t == 0) {
        out[OUT_SCALARS + 0] = red[0] * (1.f / (float)NTOK);
        out[OUT_SCALARS + 1] = expf(-ent);
        out[OUT_SCALARS + 2] = used * (1.f / (float)KCODE);
    }
}

extern "C" void kernel_launch(void* const* d_in, const int* in_sizes, int n_in,
                              void* d_out, int out_size, void* d_ws, size_t ws_size,
                              hipStream_t stream) {
    const float* z  = (const float*)d_in[0];
    const float* cb = (const float*)d_in[1];
    float* out = (float*)d_out;
    float* ws  = (float*)d_ws;   // 288 KB used

    prep_kernel  <<<4, 256, 0, stream>>>(cb, ws);
    quant_kernel <<<NTOK / 64, 256, 0, stream>>>(z, cb, out, ws);
    rescue_kernel<<<256, 256, 0, stream>>>(z, cb, out, ws);
    final_kernel <<<1, 1024, 0, stream>>>(ws, out);
}

// Round 7
// 131.442 us; speedup vs baseline: 1.5889x; 1.5889x over previous
//
#include <hip/hip_runtime.h>

// QuantizeEMAReset forward (eval): VQ quantize + commit loss + perplexity/usage.
// z: [16,4096,64] fp32 -> N=65536 tokens, C=64. codebook: [1024,64] fp32.
// out: [z_q_bar (4194304 f32), commit_loss, ppl, usage] flat.
//
// R7: T3/T4 pipeline. Codebook (hi/lo fp16 split, 4KB per 16-code tile) is
// DMA'd global->LDS via global_load_lds into a 4-slot ring, 3 tiles in
// flight, counted s_waitcnt vmcnt(2) + raw s_barrier (one per tile; no
// __syncthreads drain -> R5's per-tile full-latency stall removed; no
// register dbuf -> R6's compiler-fold failure avoided).
// prep pre-swizzles the tile stream (16B slot rotated by (d8+code)&7) so the
// linear DMA + swizzled ds_read_b128 hit the 8-cycle LDS floor.
//
// ws float-index map:
//   [0,1024)      cnorm
//   [1024,2048)   counts
//   [2048,3072)   loss partials (per block)
//   3072          nflag (int)
//   [3073,7169)   flag list (int: tok | idx<<16)
//   [8192,139264) cbhl: 64 tiles x 2048 halves (hi 1KB | lo 1KB each; 256KB)

typedef _Float16 half8 __attribute__((ext_vector_type(8)));
typedef float f32x4 __attribute__((ext_vector_type(4)));

#define NTOK 65536
#define KCODE 1024
#define OUT_SCALARS 4194304
#define MARGIN 1e-3f
#define FLAG_CAP 4096

#define WS_CNORM 0
#define WS_CNT   1024
#define WS_LOSS  2048
#define WS_NFLAG 3072
#define WS_FLAGS 3073
#define WS_CBHL  8192

static __device__ __forceinline__ unsigned int order_key(float f) {
    unsigned int u = __float_as_uint(f);
    unsigned int mask = (u >> 31) ? 0xFFFFFFFFu : 0x80000000u;
    return u ^ mask;   // monotone: a<b (float) <=> key(a)<key(b) (uint)
}

__global__ void prep_kernel(const float* __restrict__ cb, float* __restrict__ ws) {
    const int k = blockIdx.x * 256 + threadIdx.x;   // 0..1023
    const float4* cb4 = (const float4*)cb;
    float s = 0.f;
#pragma unroll
    for (int j = 0; j < 16; ++j) {
        float4 v = cb4[k * 16 + j];
        s = fmaf(v.x, v.x, s);
        s = fmaf(v.y, v.y, s);
        s = fmaf(v.z, v.z, s);
        s = fmaf(v.w, v.w, s);
    }
    ws[k] = s;             // cnorm: exact R1 chain
    ws[WS_CNT + k] = 0.f;  // zero histogram
    if (k == 0) *(int*)(ws + WS_NFLAG) = 0;

    // combined swizzled tile stream: tile = k>>4, c = k&15
    _Float16* base = (_Float16*)(ws + WS_CBHL) + (size_t)(k >> 4) * 2048 + (k & 15) * 64;
    const int c = k & 15;
#pragma unroll
    for (int d8 = 0; d8 < 8; ++d8) {
        float4 a = cb4[k * 16 + 2 * d8], b = cb4[k * 16 + 2 * d8 + 1];
        float xf[8] = {a.x, a.y, a.z, a.w, b.x, b.y, b.z, b.w};
        half8 h, lo;
#pragma unroll
        for (int i = 0; i < 8; ++i) {
            _Float16 hi = (_Float16)xf[i];
            h[i] = hi;
            lo[i] = (_Float16)((xf[i] - (float)hi) * 4096.f);  // scaled: no f16 denorm flush
        }
        const int pos = ((d8 + c) & 7) * 8;   // 16B-slot rotation (bank spread)
        *(half8*)(base + pos) = h;
        *(half8*)(base + 1024 + pos) = lo;
    }
}

__launch_bounds__(256, 4)
__global__ void quant_kernel(const float* __restrict__ z,
                             const float* __restrict__ cb,
                             float* __restrict__ out,
                             float* __restrict__ ws) {
    const int t = threadIdx.x, blk = blockIdx.x;
    const int w = t >> 6, l = t & 63;
    const int cl = l & 15, g = l >> 4;
    const int tokL = w * 16 + cl;
    const int tokG = blk * 64 + tokL;

    __shared__ __align__(16) _Float16 tiles[4][2048];   // 4-slot ring, 4KB/slot
    __shared__ __align__(16) float cn_lds[1024];
    __shared__ __align__(16) float x_lds[64 * 68];
    __shared__ int win[64];
    __shared__ float lsum[64];

    // ---- stage cnorm to LDS ----
    *(float4*)&cn_lds[t * 4] = *(const float4*)(ws + t * 4);

    // ---- B fragments (persistent regs) + x_lds staging ----
    half8 zh[2], zl[2];
    {
        const float4* z4 = (const float4*)(z + (size_t)tokG * 64);
#pragma unroll
        for (int q = 0; q < 2; ++q) {
            float4 a = z4[2 * g + 8 * q], b = z4[2 * g + 8 * q + 1];
            *(float4*)&x_lds[tokL * 68 + g * 8 + 32 * q] = a;
            *(float4*)&x_lds[tokL * 68 + g * 8 + 32 * q + 4] = b;
            float xf[8] = {a.x, a.y, a.z, a.w, b.x, b.y, b.z, b.w};
#pragma unroll
            for (int i = 0; i < 8; ++i) {
                _Float16 h = (_Float16)xf[i];
                zh[q][i] = h;
                zl[q][i] = (_Float16)((xf[i] - (float)h) * 4096.f);
            }
        }
    }

    // per-lane DMA source (lane reads its own 16B; dest = wave-uniform + lane*16)
    const char* dma_src = (const char*)(ws + WS_CBHL) + w * 1024 + l * 16;
    // swizzled fragment offsets (halves) within a tile slot
    const int o0 = cl * 64 + ((g + cl) & 7) * 8;
    const int o1 = cl * 64 + (((g + cl) & 7) ^ 4) * 8;

    float d1 = 3.4e38f, d2 = 3.4e38f;
    int idx1 = 0;

    // drain own LDS writes (cnorm, x_lds) before first raw barrier
    asm volatile("s_waitcnt lgkmcnt(0)" ::: "memory");

    // prologue: 3 tiles in flight
#pragma unroll
    for (int p = 0; p < 3; ++p) {
        __builtin_amdgcn_global_load_lds(
            (const __attribute__((address_space(1))) void*)(dma_src + p * 4096),
            (__attribute__((address_space(3))) void*)&tiles[p][w * 512], 16, 0, 0);
    }

#define TILE_BODY(ti, SLOT, VM, ISSUE)                                          \
    {                                                                           \
        asm volatile("s_waitcnt vmcnt(" VM ")" ::: "memory");                   \
        asm volatile("s_barrier" ::: "memory");                                 \
        const _Float16* tp = &tiles[SLOT][0];                                   \
        half8 H0 = *(const half8*)(tp + o0);                                    \
        half8 H1 = *(const half8*)(tp + o1);                                    \
        half8 L0 = *(const half8*)(tp + 1024 + o0);                             \
        half8 L1 = *(const half8*)(tp + 1024 + o1);                             \
        float4 cnv = *(const float4*)&cn_lds[(ti) * 16 + 4 * g];                \
        if (ISSUE)                                                              \
            __builtin_amdgcn_global_load_lds(                                   \
                (const __attribute__((address_space(1))) void*)(dma_src + ((ti) + 3) * 4096), \
                (__attribute__((address_space(3))) void*)&tiles[((ti) + 3) & 3][w * 512], \
                16, 0, 0);                                                      \
        f32x4 a1 = {0.f,0.f,0.f,0.f}, a2a = {0.f,0.f,0.f,0.f}, a2b = {0.f,0.f,0.f,0.f}; \
        a1  = __builtin_amdgcn_mfma_f32_16x16x32_f16(H0, zh[0], a1, 0, 0, 0);   \
        a1  = __builtin_amdgcn_mfma_f32_16x16x32_f16(H1, zh[1], a1, 0, 0, 0);   \
        a2a = __builtin_amdgcn_mfma_f32_16x16x32_f16(H0, zl[0], a2a, 0, 0, 0);  \
        a2a = __builtin_amdgcn_mfma_f32_16x16x32_f16(H1, zl[1], a2a, 0, 0, 0);  \
        a2b = __builtin_amdgcn_mfma_f32_16x16x32_f16(L0, zh[0], a2b, 0, 0, 0);  \
        a2b = __builtin_amdgcn_mfma_f32_16x16x32_f16(L1, zh[1], a2b, 0, 0, 0);  \
        const float cna[4] = {cnv.x, cnv.y, cnv.z, cnv.w};                      \
        _Pragma("unroll")                                                       \
        for (int r = 0; r < 4; ++r) {                                           \
            float dot = fmaf(a2a[r] + a2b[r], 2.44140625e-4f, a1[r]);           \
            float d = fmaf(-2.f, dot, cna[r]);                                  \
            const int kidx = (ti) * 16 + 4 * g + r;                             \
            bool lt = d < d1;                                                   \
            d2 = fminf(d2, fmaxf(d, d1));                                       \
            idx1 = lt ? kidx : idx1;                                            \
            d1 = fminf(d1, d);                                                  \
        }                                                                       \
    }

    // main loop: tiles 0..59 (slots static via 4x unroll), issue up to tile 62
    for (int i4 = 0; i4 < 60; i4 += 4) {
        TILE_BODY(i4 + 0, 0, "2", 1)
        TILE_BODY(i4 + 1, 1, "2", 1)
        TILE_BODY(i4 + 2, 2, "2", 1)
        TILE_BODY(i4 + 3, 3, "2", 1)
    }
    // tail: 60 issues 63; then drain
    TILE_BODY(60, 0, "2", 1)
    TILE_BODY(61, 1, "2", 0)
    TILE_BODY(62, 2, "1", 0)
    TILE_BODY(63, 3, "0", 0)
#undef TILE_BODY

    // ---- merge 4 lanes per token (lanes cl, cl+16, cl+32, cl+48) ----
    unsigned long long key = ((unsigned long long)order_key(d1) << 32) | (unsigned)idx1;
#pragma unroll
    for (int off = 16; off <= 32; off <<= 1) {
        unsigned long long ok = __shfl_xor(key, off, 64);
        float od1 = __shfl_xor(d1, off, 64);
        float od2 = __shfl_xor(d2, off, 64);
        d2 = fminf(fminf(d2, od2), fmaxf(d1, od1));  // 2nd-min of union
        d1 = fminf(d1, od1);
        key = ok < key ? ok : key;
    }
    if (l < 16) {
        const int idx = (int)(unsigned)(key & 0xFFFFFFFFull);
        win[tokL] = idx;
        atomicAdd(&ws[WS_CNT + idx], 1.f);   // integer-valued: exact, order-indep
        if (d2 - d1 < MARGIN) {              // near-tie: flag for exact rescore
            int slot = atomicAdd((int*)(ws + WS_NFLAG), 1);
            if (slot < FLAG_CAP)
                ((int*)(ws + WS_FLAGS))[slot] = tokG | (idx << 16);
        }
    }
    __syncthreads();

    // ---- fused epilogue: z_q_bar + commit-loss partial ----
    {
        const int tokr = t >> 2, fb = (t & 3) * 4;
        const int idx = win[tokr];
        const float4* cq = (const float4*)cb + (size_t)idx * 16;
        float4* o4 = (float4*)out + (size_t)(blk * 64 + tokr) * 16;
        float ss = 0.f;
#pragma unroll
        for (int j = 0; j < 4; ++j) {
            float4 xv = *(const float4*)&x_lds[tokr * 68 + (fb + j) * 4];
            float4 qv = cq[fb + j];
            float4 ov; float dx;
            dx = qv.x - xv.x; ov.x = xv.x + dx; ss = fmaf(dx, dx, ss);
            dx = qv.y - xv.y; ov.y = xv.y + dx; ss = fmaf(dx, dx, ss);
            dx = qv.z - xv.z; ov.z = xv.z + dx; ss = fmaf(dx, dx, ss);
            dx = qv.w - xv.w; ov.w = xv.w + dx; ss = fmaf(dx, dx, ss);
            o4[fb + j] = ov;
        }
        ss += __shfl_down(ss, 2, 64);
        ss += __shfl_down(ss, 1, 64);
        if ((t & 3) == 0) lsum[tokr] = ss * (1.f / 64.f);
    }
    __syncthreads();
    if (t < 64) {
        float v = lsum[t];
#pragma unroll
        for (int off = 32; off > 0; off >>= 1) v += __shfl_down(v, off, 64);
        if (t == 0) ws[WS_LOSS + blk] = v;
    }
}

// Exact fp32 rescore (R1 chain) for flagged near-tie tokens.
__global__ void rescue_kernel(const float* __restrict__ z,
                              const float* __restrict__ cb,
                              float* __restrict__ out,
                              float* __restrict__ ws) {
    const int t = threadIdx.x;
    int nf = *(const int*)(ws + WS_NFLAG);
    if (nf > FLAG_CAP) nf = FLAG_CAP;
    __shared__ float xs[64];
    __shared__ unsigned long long rk[256];
    const float4* cb4 = (const float4*)cb;

    for (int i = blockIdx.x; i < nf; i += 256) {
        const int e = ((const int*)(ws + WS_FLAGS))[i];
        const int tok = e & 0xFFFF, oldidx = e >> 16;
        __syncthreads();
        if (t < 16) *(float4*)&xs[t * 4] = ((const float4*)(z + (size_t)tok * 64))[t];
        __syncthreads();

        unsigned long long best = ~0ull;
#pragma unroll
        for (int kk = 0; kk < 4; ++kk) {
            const int k = t * 4 + kk;
            float s = 0.f;
#pragma unroll
            for (int j = 0; j < 16; ++j) {
                float4 c = cb4[(size_t)k * 16 + j];
                float4 xv = *(const float4*)&xs[j * 4];
                s = fmaf(xv.x, c.x, s);
                s = fmaf(xv.y, c.y, s);
                s = fmaf(xv.z, c.z, s);
                s = fmaf(xv.w, c.w, s);
            }
            float d = fmaf(-2.f, s, ws[k]);   // exact R1 distance
            unsigned long long kkey = ((unsigned long long)order_key(d) << 32) | (unsigned)k;
            best = kkey < best ? kkey : best;
        }
        rk[t] = best; __syncthreads();
        for (int sft = 128; sft > 0; sft >>= 1) {
            if (t < sft) { unsigned long long o = rk[t + sft]; if (o < rk[t]) rk[t] = o; }
            __syncthreads();
        }
        if (t == 0) {
            const int ni = (int)(unsigned)(rk[0] & 0xFFFFFFFFull);
            if (ni != oldidx) {
                atomicAdd(&ws[WS_CNT + oldidx], -1.f);
                atomicAdd(&ws[WS_CNT + ni], 1.f);
                const float4* co = cb4 + (size_t)oldidx * 16;
                const float4* cn = cb4 + (size_t)ni * 16;
                float4* o4 = (float4*)out + (size_t)tok * 16;
                float sg_o[4], sg_n[4];
#pragma unroll
                for (int gq = 0; gq < 4; ++gq) {
                    float so = 0.f, sn = 0.f;
#pragma unroll
                    for (int j = 0; j < 4; ++j) {
                        float4 xv = *(const float4*)&xs[(gq * 4 + j) * 4];
                        float4 qo = co[gq * 4 + j], qn = cn[gq * 4 + j];
                        float dx;
                        dx = qo.x - xv.x; so = fmaf(dx, dx, so);
                        dx = qo.y - xv.y; so = fmaf(dx, dx, so);
                        dx = qo.z - xv.z; so = fmaf(dx, dx, so);
                        dx = qo.w - xv.w; so = fmaf(dx, dx, so);
                        float4 ov;
                        dx = qn.x - xv.x; ov.x = xv.x + dx; sn = fmaf(dx, dx, sn);
                        dx = qn.y - xv.y; ov.y = xv.y + dx; sn = fmaf(dx, dx, sn);
                        dx = qn.z - xv.z; ov.z = xv.z + dx; sn = fmaf(dx, dx, sn);
                        dx = qn.w - xv.w; ov.w = xv.w + dx; sn = fmaf(dx, dx, sn);
                        o4[gq * 4 + j] = ov;
                    }
                    sg_o[gq] = so; sg_n[gq] = sn;
                }
                float sso = (sg_o[0] + sg_o[2]) + (sg_o[1] + sg_o[3]);  // match quant shfl tree
                float ssn = (sg_n[0] + sg_n[2]) + (sg_n[1] + sg_n[3]);
                atomicAdd(&ws[WS_LOSS + (tok >> 6)], (ssn - sso) * (1.f / 64.f));
            }
        }
    }
}

__global__ void final_kernel(const float* __restrict__ ws, float* __restrict__ out) {
    __shared__ float red[1024];
    const int t = threadIdx.x;
    const float c = ws[WS_CNT + t];

    red[t] = c; __syncthreads();
    for (int s = 512; s > 0; s >>= 1) { if (t < s) red[t] += red[t + s]; __syncthreads(); }
    const float total = fmaxf(red[0], 1e-6f);
    __syncthreads();

    const float p = c / total;
    red[t] = p * logf(p + 1e-7f); __syncthreads();
    for (int s = 512; s > 0; s >>= 1) { if (t < s) red[t] += red[t + s]; __syncthreads(); }
    const float ent = red[0];
    __syncthreads();

    red[t] = (c >= 1.f) ? 1.f : 0.f; __syncthreads();
    for (int s = 512; s > 0; s >>= 1) { if (t < s) red[t] += red[t + s]; __syncthreads(); }
    const float used = red[0];
    __syncthreads();

    red[t] = ws[WS_LOSS + t];   // 1024 block partials
    __syncthreads();
    for (int s = 512; s > 0; s >>= 1) { if (t < s) red[t] += red[t + s]; __syncthreads(); }

    if (t == 0) {
        out[OUT_SCALARS + 0] = red[0] * (1.f / (float)NTOK);
        out[OUT_SCALARS + 1] = expf(-ent);
        out[OUT_SCALARS + 2] = used * (1.f / (float)KCODE);
    }
}

extern "C" void kernel_launch(void* const* d_in, const int* in_sizes, int n_in,
                              void* d_out, int out_size, void* d_ws, size_t ws_size,
                              hipStream_t stream) {
    const float* z  = (const float*)d_in[0];
    const float* cb = (const float*)d_in[1];
    float* out = (float*)d_out;
    float* ws  = (float*)d_ws;   // ~295 KB used

    prep_kernel  <<<4, 256, 0, stream>>>(cb, ws);
    quant_kernel <<<NTOK / 64, 256, 0, stream>>>(z, cb, out, ws);
    rescue_kernel<<<256, 256, 0, stream>>>(z, cb, out, ws);
    final_kernel <<<1, 1024, 0, stream>>>(ws, out);
}

// Round 9
// 101.497 us; speedup vs baseline: 2.0577x; 1.2950x over previous
//
#include <hip/hip_runtime.h>

// QuantizeEMAReset forward (eval): VQ quantize + commit loss + perplexity/usage.
// z: [16,4096,64] fp32 -> N=65536 tokens, C=64. codebook: [1024,64] fp32.
// out: [z_q_bar (4194304 f32), commit_loss, ppl, usage] flat.
//
// R9: R7's PROVEN barrier'd DMA pipeline (vmcnt(2)+s_barrier per tile, block-
// shared 4-slot ring, absmax 0.0) + two B-frag sets (32 tok/wave, 12 MFMA per
// barrier, grid 512) + in-wave exact fp32 rescue for near-ties (standalone
// rescue kernel deleted; it idled 45-110us). vmcnt hygiene: pin with
// s_waitcnt vmcnt(0)+sched_barrier(0) before the DMA prologue so in-loop
// vmcnt counts ONLY the global_load_lds stream (R8's suspected failure).
//
// ws float-index map:
//   [0,1024)      cnorm
//   [1024,2048)   counts
//   [2048,2560)   loss partials (512 blocks)
//   [8192,73728)  cbhl tile stream: 64 tiles x 2048 halves (hi 1KB | lo 1KB)

typedef _Float16 half8 __attribute__((ext_vector_type(8)));
typedef float f32x4 __attribute__((ext_vector_type(4)));

#define NTOK 65536
#define KCODE 1024
#define OUT_SCALARS 4194304
#define MARGIN 1e-3f

#define WS_CNT   1024
#define WS_LOSS  2048
#define WS_CBHL  8192

static __device__ __forceinline__ unsigned int order_key(float f) {
    unsigned int u = __float_as_uint(f);
    unsigned int mask = (u >> 31) ? 0xFFFFFFFFu : 0x80000000u;
    return u ^ mask;   // monotone: a<b (float) <=> key(a)<key(b) (uint)
}

__global__ void prep_kernel(const float* __restrict__ cb, float* __restrict__ ws) {
    const int k = blockIdx.x * 256 + threadIdx.x;   // 0..1023
    const float4* cb4 = (const float4*)cb;
    float s = 0.f;
#pragma unroll
    for (int j = 0; j < 16; ++j) {
        float4 v = cb4[k * 16 + j];
        s = fmaf(v.x, v.x, s);
        s = fmaf(v.y, v.y, s);
        s = fmaf(v.z, v.z, s);
        s = fmaf(v.w, v.w, s);
    }
    ws[k] = s;             // cnorm: exact R1 chain
    ws[WS_CNT + k] = 0.f;  // zero histogram

    // swizzled tile stream: tile = k>>4, c = k&15
    _Float16* base = (_Float16*)(ws + WS_CBHL) + (size_t)(k >> 4) * 2048 + (k & 15) * 64;
    const int c = k & 15;
#pragma unroll
    for (int d8 = 0; d8 < 8; ++d8) {
        float4 a = cb4[k * 16 + 2 * d8], b = cb4[k * 16 + 2 * d8 + 1];
        float xf[8] = {a.x, a.y, a.z, a.w, b.x, b.y, b.z, b.w};
        half8 h, lo;
#pragma unroll
        for (int i = 0; i < 8; ++i) {
            _Float16 hi = (_Float16)xf[i];
            h[i] = hi;
            lo[i] = (_Float16)((xf[i] - (float)hi) * 4096.f);  // scaled: no f16 denorm flush
        }
        const int pos = ((d8 + c) & 7) * 8;   // 16B-slot rotation (bank spread)
        *(half8*)(base + pos) = h;
        *(half8*)(base + 1024 + pos) = lo;
    }
}

__launch_bounds__(256, 2)
__global__ void quant_kernel(const float* __restrict__ z,
                             const float* __restrict__ cb,
                             float* __restrict__ out,
                             float* __restrict__ ws) {
    const int t = threadIdx.x, blk = blockIdx.x;
    const int w = t >> 6, l = t & 63;
    const int cl = l & 15, g = l >> 4;
    const int tokW = blk * 128 + w * 32;    // wave's first token (2 sets of 16)

    __shared__ __align__(16) _Float16 tiles[4][2048];   // block-shared 4-slot ring
    __shared__ __align__(16) float cn_lds[1024];
    __shared__ int win[128];
    __shared__ float lsum[128];

    // ---- stage cnorm to LDS ----
    *(float4*)&cn_lds[t * 4] = *(const float4*)(ws + t * 4);

    // ---- B fragments: 2 token sets of 16 (persistent regs) ----
    half8 zh0[2], zl0[2], zh1[2], zl1[2];
#define MKFRAG(ZH, ZL, TOK)                                                \
    {                                                                      \
        const float4* z4 = (const float4*)z + (size_t)(TOK) * 16;          \
        _Pragma("unroll")                                                  \
        for (int q = 0; q < 2; ++q) {                                      \
            float4 a = z4[2 * g + 8 * q], b = z4[2 * g + 8 * q + 1];       \
            float xf[8] = {a.x, a.y, a.z, a.w, b.x, b.y, b.z, b.w};        \
            _Pragma("unroll")                                              \
            for (int i = 0; i < 8; ++i) {                                  \
                _Float16 h = (_Float16)xf[i];                              \
                ZH[q][i] = h;                                              \
                ZL[q][i] = (_Float16)((xf[i] - (float)h) * 4096.f);        \
            }                                                              \
        }                                                                  \
    }
    MKFRAG(zh0, zl0, tokW + cl)
    MKFRAG(zh1, zl1, tokW + 16 + cl)
#undef MKFRAG

    // PIN: all z-loads + LDS writes complete; nothing crosses this point.
    // In-loop vmcnt then counts ONLY the global_load_lds DMA stream.
    asm volatile("s_waitcnt vmcnt(0) lgkmcnt(0)" ::: "memory");
    __builtin_amdgcn_sched_barrier(0);

    // per-wave DMA src: wave w stages quarter w of each tile (1 DMA/tile/wave)
    const char* dma_src = (const char*)(ws + WS_CBHL) + w * 1024 + l * 16;
    const int rot = (g + cl) & 7;
    const int o0 = cl * 64 + rot * 8;
    const int o1 = cl * 64 + (rot ^ 4) * 8;

    // prologue: 3 tiles in flight
#pragma unroll
    for (int p = 0; p < 3; ++p) {
        __builtin_amdgcn_global_load_lds(
            (const __attribute__((address_space(1))) void*)(dma_src + p * 4096),
            (__attribute__((address_space(3))) void*)&tiles[p][w * 512], 16, 0, 0);
    }

    float d1a = 3.4e38f, d2a = 3.4e38f, d1b = 3.4e38f, d2b = 3.4e38f;
    int idxa = 0, idxb = 0;

#define ARGMIN(A1, A2, A3, D1, D2, IDX, ti)                                 \
    _Pragma("unroll")                                                       \
    for (int r = 0; r < 4; ++r) {                                           \
        float dot = fmaf(A2[r] + A3[r], 2.44140625e-4f, A1[r]);             \
        float d = fmaf(-2.f, dot, cna[r]);                                  \
        const int kidx = (ti) * 16 + 4 * g + r;                             \
        bool lt = d < D1;                                                   \
        D2 = fminf(D2, fmaxf(d, D1));                                       \
        IDX = lt ? kidx : IDX;                                              \
        D1 = fminf(D1, d);                                                  \
    }

#define TILE_BODY(ti, SLOT, VM, ISSUE)                                                \
    {                                                                                 \
        asm volatile("s_waitcnt vmcnt(" VM ")" ::: "memory");                         \
        asm volatile("s_barrier" ::: "memory");                                       \
        const _Float16* tp = &tiles[SLOT][0];                                         \
        half8 H0 = *(const half8*)(tp + o0);                                          \
        half8 H1 = *(const half8*)(tp + o1);                                          \
        half8 L0 = *(const half8*)(tp + 1024 + o0);                                   \
        half8 L1 = *(const half8*)(tp + 1024 + o1);                                   \
        float4 cnv = *(const float4*)&cn_lds[(ti) * 16 + 4 * g];                      \
        const float cna[4] = {cnv.x, cnv.y, cnv.z, cnv.w};                            \
        if (ISSUE)                                                                    \
            __builtin_amdgcn_global_load_lds(                                         \
                (const __attribute__((address_space(1))) void*)(dma_src + ((ti) + 3) * 4096), \
                (__attribute__((address_space(3))) void*)&tiles[((ti) + 3) & 3][w * 512], \
                16, 0, 0);                                                            \
        f32x4 p1a = {0.f,0.f,0.f,0.f}, p2a = {0.f,0.f,0.f,0.f}, p3a = {0.f,0.f,0.f,0.f}; \
        f32x4 p1b = {0.f,0.f,0.f,0.f}, p2b = {0.f,0.f,0.f,0.f}, p3b = {0.f,0.f,0.f,0.f}; \
        p1a = __builtin_amdgcn_mfma_f32_16x16x32_f16(H0, zh0[0], p1a, 0, 0, 0);       \
        p1a = __builtin_amdgcn_mfma_f32_16x16x32_f16(H1, zh0[1], p1a, 0, 0, 0);       \
        p1b = __builtin_amdgcn_mfma_f32_16x16x32_f16(H0, zh1[0], p1b, 0, 0, 0);       \
        p1b = __builtin_amdgcn_mfma_f32_16x16x32_f16(H1, zh1[1], p1b, 0, 0, 0);       \
        p2a = __builtin_amdgcn_mfma_f32_16x16x32_f16(H0, zl0[0], p2a, 0, 0, 0);       \
        p2a = __builtin_amdgcn_mfma_f32_16x16x32_f16(H1, zl0[1], p2a, 0, 0, 0);       \
        p2b = __builtin_amdgcn_mfma_f32_16x16x32_f16(H0, zl1[0], p2b, 0, 0, 0);       \
        p2b = __builtin_amdgcn_mfma_f32_16x16x32_f16(H1, zl1[1], p2b, 0, 0, 0);       \
        p3a = __builtin_amdgcn_mfma_f32_16x16x32_f16(L0, zh0[0], p3a, 0, 0, 0);       \
        p3a = __builtin_amdgcn_mfma_f32_16x16x32_f16(L1, zh0[1], p3a, 0, 0, 0);       \
        p3b = __builtin_amdgcn_mfma_f32_16x16x32_f16(L0, zh1[0], p3b, 0, 0, 0);       \
        p3b = __builtin_amdgcn_mfma_f32_16x16x32_f16(L1, zh1[1], p3b, 0, 0, 0);       \
        ARGMIN(p1a, p2a, p3a, d1a, d2a, idxa, ti)                                     \
        ARGMIN(p1b, p2b, p3b, d1b, d2b, idxb, ti)                                     \
    }

    for (int i4 = 0; i4 < 60; i4 += 4) {
        TILE_BODY(i4 + 0, 0, "2", 1)
        TILE_BODY(i4 + 1, 1, "2", 1)
        TILE_BODY(i4 + 2, 2, "2", 1)
        TILE_BODY(i4 + 3, 3, "2", 1)
    }
    TILE_BODY(60, 0, "2", 1)   // issues tile 63
    TILE_BODY(61, 1, "2", 0)
    TILE_BODY(62, 2, "1", 0)
    TILE_BODY(63, 3, "0", 0)
#undef TILE_BODY
#undef ARGMIN

    // ---- merge 4 lanes per token (xor 16, 32) for each set ----
#define MERGE(D1, D2, KEY)                                                  \
    _Pragma("unroll")                                                       \
    for (int off = 16; off <= 32; off <<= 1) {                              \
        unsigned long long ok = __shfl_xor(KEY, off, 64);                   \
        float od1 = __shfl_xor(D1, off, 64);                                \
        float od2 = __shfl_xor(D2, off, 64);                                \
        D2 = fminf(fminf(D2, od2), fmaxf(D1, od1));                         \
        D1 = fminf(D1, od1);                                                \
        KEY = ok < KEY ? ok : KEY;                                          \
    }
    unsigned long long keyA = ((unsigned long long)order_key(d1a) << 32) | (unsigned)idxa;
    unsigned long long keyB = ((unsigned long long)order_key(d1b) << 32) | (unsigned)idxb;
    MERGE(d1a, d2a, keyA)
    MERGE(d1b, d2b, keyB)
#undef MERGE
    int fidxA = (int)(unsigned)(keyA & 0xFFFFFFFFull);
    int fidxB = (int)(unsigned)(keyB & 0xFFFFFFFFull);

    // ---- in-wave exact fp32 rescue for near-ties (rare) ----
    unsigned long long mask =
        (__ballot((l < 16) && (d2a - d1a < MARGIN)) & 0xFFFFull) |
        ((__ballot((l < 16) && (d2b - d1b < MARGIN)) & 0xFFFFull) << 16);
    while (mask) {
        const int b = __ffsll((long long)mask) - 1;   // wave-uniform
        mask &= mask - 1;
        const int tokR = tokW + b;                    // b<16: set A; else set B
        const float4* zr = (const float4*)z + (size_t)tokR * 16;
        float4 xv[16];
#pragma unroll
        for (int j = 0; j < 16; ++j) xv[j] = zr[j];   // broadcast load
        unsigned long long bk = ~0ull;
#pragma unroll 4
        for (int q = 0; q < 16; ++q) {
            const int k = l + q * 64;
            const float4* cr = (const float4*)cb + (size_t)k * 16;
            float s = 0.f;
#pragma unroll
            for (int j = 0; j < 16; ++j) {
                float4 c = cr[j];
                s = fmaf(xv[j].x, c.x, s);
                s = fmaf(xv[j].y, c.y, s);
                s = fmaf(xv[j].z, c.z, s);
                s = fmaf(xv[j].w, c.w, s);
            }
            float d = fmaf(-2.f, s, cn_lds[k]);   // exact R1 distance
            unsigned long long kk = ((unsigned long long)order_key(d) << 32) | (unsigned)k;
            bk = kk < bk ? kk : bk;
        }
#pragma unroll
        for (int off = 1; off < 64; off <<= 1) {
            unsigned long long o = __shfl_xor(bk, off, 64);
            bk = o < bk ? o : bk;
        }
        const int ni = (int)(unsigned)(bk & 0xFFFFFFFFull);
        if (l == (b & 15)) {
            if (b < 16) fidxA = ni; else fidxB = ni;
        }
    }

    // ---- commit winners ----
    if (l < 16) {
        win[w * 32 + l] = fidxA;
        win[w * 32 + 16 + l] = fidxB;
        atomicAdd(&ws[WS_CNT + fidxA], 1.f);   // integer-valued: exact, order-indep
        atomicAdd(&ws[WS_CNT + fidxB], 1.f);
    }
    __syncthreads();

    // ---- fused epilogue: z_q_bar + commit-loss partial (z re-read, L2-hot) ----
    {
        const int lt = t >> 1, h = t & 1;       // 2 threads per token
        const int tokE = blk * 128 + lt;
        const int idx = win[lt];
        const float4* zr = (const float4*)z + (size_t)tokE * 16 + h * 8;
        const float4* cq = (const float4*)cb + (size_t)idx * 16 + h * 8;
        float4* o4 = (float4*)out + (size_t)tokE * 16 + h * 8;
        float ss = 0.f;
#pragma unroll
        for (int j = 0; j < 8; ++j) {
            float4 xvv = zr[j];
            float4 qv = cq[j];
            float4 ov; float dx;
            dx = qv.x - xvv.x; ov.x = xvv.x + dx; ss = fmaf(dx, dx, ss);
            dx = qv.y - xvv.y; ov.y = xvv.y + dx; ss = fmaf(dx, dx, ss);
            dx = qv.z - xvv.z; ov.z = xvv.z + dx; ss = fmaf(dx, dx, ss);
            dx = qv.w - xvv.w; ov.w = xvv.w + dx; ss = fmaf(dx, dx, ss);
            o4[j] = ov;
        }
        float os = __shfl_down(ss, 1, 64);      // partner lane (same token)
        if (h == 0) lsum[lt] = (ss + os) * (1.f / 64.f);
    }
    __syncthreads();
    if (t < 64) {
        float v = lsum[t] + lsum[t + 64];
#pragma unroll
        for (int off = 32; off > 0; off >>= 1) v += __shfl_down(v, off, 64);
        if (t == 0) ws[WS_LOSS + blk] = v;
    }
}

__global__ void final_kernel(const float* __restrict__ ws, float* __restrict__ out) {
    __shared__ float red[1024];
    const int t = threadIdx.x;
    const float c = ws[WS_CNT + t];

    red[t] = c; __syncthreads();
    for (int s = 512; s > 0; s >>= 1) { if (t < s) red[t] += red[t + s]; __syncthreads(); }
    const float total = fmaxf(red[0], 1e-6f);
    __syncthreads();

    const float p = c / total;
    red[t] = p * logf(p + 1e-7f); __syncthreads();
    for (int s = 512; s > 0; s >>= 1) { if (t < s) red[t] += red[t + s]; __syncthreads(); }
    const float ent = red[0];
    __syncthreads();

    red[t] = (c >= 1.f) ? 1.f : 0.f; __syncthreads();
    for (int s = 512; s > 0; s >>= 1) { if (t < s) red[t] += red[t + s]; __syncthreads(); }
    const float used = red[0];
    __syncthreads();

    red[t] = (t < 512) ? ws[WS_LOSS + t] : 0.f;   // 512 block partials
    __syncthreads();
    for (int s = 512; s > 0; s >>= 1) { if (t < s) red[t] += red[t + s]; __syncthreads(); }

    if (t == 0) {
        out[OUT_SCALARS + 0] = red[0] * (1.f / (float)NTOK);
        out[OUT_SCALARS + 1] = expf(-ent);
        out[OUT_SCALARS + 2] = used * (1.f / (float)KCODE);
    }
}

extern "C" void kernel_launch(void* const* d_in, const int* in_sizes, int n_in,
                              void* d_out, int out_size, void* d_ws, size_t ws_size,
                              hipStream_t stream) {
    const float* z  = (const float*)d_in[0];
    const float* cb = (const float*)d_in[1];
    float* out = (float*)d_out;
    float* ws  = (float*)d_ws;   // ~295 KB used

    prep_kernel <<<4, 256, 0, stream>>>(cb, ws);
    quant_kernel<<<NTOK / 128, 256, 0, stream>>>(z, cb, out, ws);
    final_kernel<<<1, 1024, 0, stream>>>(ws, out);
}